// Round 19
// baseline (79.248 us; speedup 1.0000x reference)
//
#include <hip/hip_runtime.h>
#include <hip/hip_bf16.h>
#include <math.h>

// Problem constants (fixed by setup_inputs)
constexpr int B_ = 2, T_ = 2048, C_ = 512, H_ = 8, D_ = 64;
constexpr int QKVG_ = 3 * H_ * D_ + H_;   // 1544 (w_attn row stride)
constexpr float GATE_BIAS_ = 6.906768f;
constexpr int N1_ = 1536;                 // gemm1 N (Q,K,V only; gate separate)
constexpr int SC_ = 8;                    // s-tiles per attn chunk
constexpr int NBLK_ = 1280;               // attn blocks (16 bh x 80)
constexpr int MC_ = 4096 * 512;           // 2,097,152
constexpr int BHT_ = B_ * H_ * T_;        // 32,768

typedef __attribute__((ext_vector_type(8))) short short8;
typedef __attribute__((ext_vector_type(4))) float f32x4;

// hardware RNE f32->bf16 (compiler fuses pairs into v_cvt_pk_bf16_f32)
__device__ __forceinline__ unsigned short f2b(float f) {
    union { __hip_bfloat16 h; unsigned short u; } cv;
    cv.h = __float2bfloat16(f);
    return cv.u;
}
__device__ __forceinline__ float b2f(unsigned short u) {
    return __uint_as_float((unsigned int)u << 16);
}
__device__ __forceinline__ short8 pack8(float4 a, float4 b) {
    short8 r;
    r[0] = (short)f2b(a.x); r[1] = (short)f2b(a.y);
    r[2] = (short)f2b(a.z); r[3] = (short)f2b(a.w);
    r[4] = (short)f2b(b.x); r[5] = (short)f2b(b.y);
    r[6] = (short)f2b(b.z); r[7] = (short)f2b(b.w);
    return r;
}

// async global->LDS, 16 B/lane
__device__ __forceinline__ void gl2lds16(const unsigned short* g, void* lds_base) {
    __builtin_amdgcn_global_load_lds(
        (const __attribute__((address_space(1))) unsigned int*)g,
        (__attribute__((address_space(3))) unsigned int*)lds_base, 16, 0, 0);
}

// ---------------------------------------------------------------------------
// pack_inputs: [0,1024) x->xb (pre-swz) | [1024,1216) w_attn->Bt1 (24x8) |
// [1216,1280) w_proj->Bt2 (8x8) | [1280,1288) sincos table | [1288,1416) gate GEMV
// ---------------------------------------------------------------------------
__device__ __forceinline__ void packT_body(
    const float* __restrict__ W, unsigned short* __restrict__ Bt,
    int K, int N, int ldW, int nt, int kt, int tid, float (*Ws)[65])
{
    {
        const int r = tid >> 2;
        const int c0 = (tid & 3) * 16;
#pragma unroll
        for (int j = 0; j < 16; ++j) {
            const int n = nt + c0 + j;
            Ws[r][c0 + j] = (n < N) ? W[(size_t)(kt + r) * ldW + n] : 0.f;
        }
    }
    __syncthreads();
    {
        const int d = tid >> 2;
        const int cc = tid & 3;
        const int kc = cc * 16;
        short8 o0, o1;
#pragma unroll
        for (int j = 0; j < 8; ++j) o0[j] = (short)f2b(Ws[kc + j][d]);
#pragma unroll
        for (int j = 0; j < 8; ++j) o1[j] = (short)f2b(Ws[kc + 8 + j][d]);
        const int row = nt + d;
        unsigned short* op = Bt + (size_t)row * K + kt;
        *(short8*)(op + ((2 * cc) ^ (row & 7)) * 8)     = o0;
        *(short8*)(op + ((2 * cc + 1) ^ (row & 7)) * 8) = o1;
    }
}

__global__ __launch_bounds__(256) void pack_inputs(
    const float* __restrict__ x, const float* __restrict__ w_attn,
    const float* __restrict__ w_proj, unsigned short* __restrict__ xb,
    unsigned short* __restrict__ Bt1, unsigned short* __restrict__ Bt2,
    float2* __restrict__ sincos, float* __restrict__ g)
{
    __shared__ float SM[64 * 65];
    float (*Ws)[65] = (float(*)[65])SM;
    const int bid = blockIdx.x;
    const int tid = threadIdx.x;
    if (bid < 1024) {
        const int i = bid * 256 + tid;
        float4 f0 = *(const float4*)(x + (size_t)i * 8);
        float4 f1 = *(const float4*)(x + (size_t)i * 8 + 4);
        const int row = i >> 6;
        const int ic = i & 63;
        const int swc = (ic & ~7) | ((ic & 7) ^ (row & 7));
        *(short8*)(xb + (size_t)row * 512 + swc * 8) = pack8(f0, f1);
    } else if (bid < 1216) {
        const int q = bid - 1024;
        packT_body(w_attn, Bt1, C_, N1_, QKVG_, (q % 24) * 64, (q / 24) * 64, tid, Ws);
    } else if (bid < 1280) {
        const int q = bid - 1216;
        packT_body(w_proj, Bt2, H_ * D_, C_, C_, (q & 7) * 64, (q >> 3) * 64, tid, Ws);
    } else if (bid < 1288) {
        const int t = (bid - 1280) * 256 + tid;
        float2* op = sincos + (size_t)t * 32;
#pragma unroll
        for (int i = 0; i < 32; ++i) {
            const float div = 6.2831853071795864f * exp2f((float)i * (-11.0f / 32.0f));
            const float ang = (float)t * div;
            op[i] = make_float2(cosf(ang), sinf(ang));
        }
    } else {
        // gate GEMV: g[bh][t] = x[m] . w_attn[:,1536+h]
        const int q = bid - 1288;
        float* LDSw = SM;                      // [512][8]
        {
            const int k = tid * 2;
#pragma unroll
            for (int kk = 0; kk < 2; ++kk) {
                const float* wp = w_attn + (size_t)(k + kk) * QKVG_ + 1536;
                float4 wa = *(const float4*)wp;
                float4 wb = *(const float4*)(wp + 4);
                float* dst = LDSw + (k + kk) * 8;
                *(float4*)dst = wa;
                *(float4*)(dst + 4) = wb;
            }
        }
        __syncthreads();
        const int m = q * 32 + (tid >> 3);
        const int h = tid & 7;
        const float* xrow = x + (size_t)m * C_;
        float s = 0.f;
#pragma unroll 4
        for (int k0 = 0; k0 < 512; k0 += 4) {
            float4 xv = *(const float4*)(xrow + k0);
            s += xv.x * LDSw[(k0 + 0) * 8 + h] + xv.y * LDSw[(k0 + 1) * 8 + h]
               + xv.z * LDSw[(k0 + 2) * 8 + h] + xv.w * LDSw[(k0 + 3) * 8 + h];
        }
        const int b = m >> 11, t = m & 2047;
        g[(size_t)(b * 8 + h) * T_ + t] = s;
    }
}

// ---------------------------------------------------------------------------
// gate_cumsum: one block per (b,h): log-sigmoid(g+bias) + block inclusive scan
// ---------------------------------------------------------------------------
__global__ __launch_bounds__(256) void gate_cumsum(
    const float* __restrict__ g, float* __restrict__ Lg)
{
    __shared__ float wsum[4];
    const int bh = blockIdx.x;
    const int tid = threadIdx.x;
    const int lane = tid & 63, wv = tid >> 6;

    const float* gp = g + (size_t)bh * T_ + tid * 8;
    float v[8];
    float s = 0.f;
#pragma unroll
    for (int j = 0; j < 8; ++j) {
        const float z = gp[j] + GATE_BIAS_;
        const float lg = (z > 0.f) ? -log1pf(expf(-z)) : (z - log1pf(expf(z)));
        s += lg;
        v[j] = s;
    }
    float ssum = s;
#pragma unroll
    for (int off = 1; off < 64; off <<= 1) {
        float n = __shfl_up(ssum, off, 64);
        if (lane >= off) ssum += n;
    }
    if (lane == 63) wsum[wv] = ssum;
    __syncthreads();
    float base = ssum - s;
#pragma unroll
    for (int w = 0; w < 3; ++w)
        base += (w < wv) ? wsum[w] : 0.f;

    float* op = Lg + (size_t)bh * T_ + tid * 8;
#pragma unroll
    for (int j = 0; j < 8; ++j) op[j] = v[j] + base;
}

// ---------------------------------------------------------------------------
// gemm_fused: qkv = xb @ Bt1^T (MFMA, N=1536), double-buffered gl2lds staging,
// fused epilogue -> Qsb / Ksb(swz) / Vtb(transposed, swz)
// ---------------------------------------------------------------------------
__global__ __launch_bounds__(256) void gemm_fused(
    const unsigned short* __restrict__ A, const unsigned short* __restrict__ Bt,
    const float* __restrict__ Lg, const float2* __restrict__ sincos,
    unsigned short* __restrict__ Qsb, unsigned short* __restrict__ Ksb,
    unsigned short* __restrict__ Vtb)
{
    __shared__ __align__(16) char smem[65536];
    float (*epi)[65] = (float(*)[65])smem;

    const int tid = threadIdx.x;
    const int wave = tid >> 6, lane = tid & 63;
    const int l15 = lane & 15, lhi = lane >> 4;
    const int wr = wave >> 1, wc = wave & 1;
    const int bm = blockIdx.y * 128, bn = blockIdx.x * 128;

    f32x4 acc[4][4];
#pragma unroll
    for (int i = 0; i < 4; ++i)
#pragma unroll
        for (int j = 0; j < 4; ++j) acc[i][j] = (f32x4){0.f, 0.f, 0.f, 0.f};

    const unsigned short* Arow = A + (size_t)bm * C_;
    const unsigned short* Brow = Bt + (size_t)bn * C_;
    const int sw = (l15 & 7) << 4;
    const int srow = tid >> 3;
    const int schunk = tid & 7;

    // prologue: stage k-step 0 into buffer 0
#pragma unroll
    for (int p = 0; p < 4; ++p) {
        const int row = p * 32 + srow;
        const size_t goff = (size_t)row * C_ + schunk * 8;
        gl2lds16(Arow + goff, smem + p * 4096 + wave * 1024);
        gl2lds16(Brow + goff, smem + 16384 + p * 4096 + wave * 1024);
    }

    for (int ks = 0; ks < 8; ++ks) {
        __syncthreads();
        if (ks < 7) {
            char* dst = smem + ((ks + 1) & 1) * 32768;
            const int k1 = (ks + 1) * 64;
#pragma unroll
            for (int p = 0; p < 4; ++p) {
                const int row = p * 32 + srow;
                const size_t goff = (size_t)row * C_ + k1 + schunk * 8;
                gl2lds16(Arow + goff, dst + p * 4096 + wave * 1024);
                gl2lds16(Brow + goff, dst + 16384 + p * 4096 + wave * 1024);
            }
        }
        const char* AsB = smem + (ks & 1) * 32768;
        const char* BsB = AsB + 16384;

        short8 af[4][2];
#pragma unroll
        for (int mi = 0; mi < 4; ++mi) {
            const int row = wr * 64 + mi * 16 + l15;
#pragma unroll
            for (int kk = 0; kk < 2; ++kk)
                af[mi][kk] = *(const short8*)(AsB + row * 128 + ((kk * 64 + lhi * 16) ^ sw));
        }
#pragma unroll
        for (int ni = 0; ni < 4; ++ni) {
            const int row = wc * 64 + ni * 16 + l15;
            short8 bf0 = *(const short8*)(BsB + row * 128 + ((lhi * 16) ^ sw));
            short8 bf1 = *(const short8*)(BsB + row * 128 + ((64 + lhi * 16) ^ sw));
#pragma unroll
            for (int mi = 0; mi < 4; ++mi) {
                acc[mi][ni] = __builtin_amdgcn_mfma_f32_16x16x32_bf16(af[mi][0], bf0, acc[mi][ni], 0, 0, 0);
                acc[mi][ni] = __builtin_amdgcn_mfma_f32_16x16x32_bf16(af[mi][1], bf1, acc[mi][ni], 0, 0, 0);
            }
        }
    }

    // -------- fused epilogue --------
    const int rid = bn >> 9;              // 0 Q, 1 K, 2 V
    const int b = bm >> 11;
    const int tloc0 = bm & 2047;

#pragma unroll
    for (int hc = 0; hc < 2; ++hc) {
        __syncthreads();
        if (wc == hc) {
#pragma unroll
            for (int mi = 0; mi < 4; ++mi)
#pragma unroll
                for (int ni = 0; ni < 4; ++ni)
#pragma unroll
                    for (int r = 0; r < 4; ++r)
                        epi[wr * 64 + mi * 16 + lhi * 4 + r][ni * 16 + l15] = acc[mi][ni][r];
        }
        __syncthreads();
        const int h = ((bn & 511) >> 6) + hc;
        const int bh = b * 8 + h;
        if (rid < 2) {
            const int row = tid >> 1;
            const int c0 = (tid & 1) * 32;
            const int t = tloc0 + row;
            const float Lt = Lg[(size_t)bh * T_ + t];
            const float scl = (rid == 0) ? (__expf(0.5f * Lt) * 0.125f)
                                         : __expf(-0.5f * Lt);
            float vb[32];
#pragma unroll
            for (int j = 0; j < 32; ++j) vb[j] = epi[row][c0 + j];
            const float2* sct = sincos + (size_t)t * 32 + (c0 >> 1);
#pragma unroll
            for (int p = 0; p < 16; ++p) {
                const float2 cssn = sct[p];
                const float x1 = vb[2 * p], x2 = vb[2 * p + 1];
                vb[2 * p]     = (x1 * cssn.x - x2 * cssn.y) * scl;
                vb[2 * p + 1] = (x2 * cssn.x + x1 * cssn.y) * scl;
            }
            unsigned short* op = ((rid == 0) ? Qsb : Ksb) + ((size_t)bh * T_ + t) * 64;
#pragma unroll
            for (int j = 0; j < 4; ++j) {
                short8 o = pack8(*(float4*)&vb[j * 8], *(float4*)&vb[j * 8 + 4]);
                const int chunk = (c0 >> 3) + j;
                const int pos = (rid == 0) ? chunk : (chunk ^ (t & 7));
                *(short8*)(op + pos * 8) = o;
            }
        } else {
            const int d = tid >> 2;
            const int tq = tid & 3;
            unsigned short* op = Vtb + ((size_t)(bh * 64 + d)) * T_;
#pragma unroll
            for (int j = 0; j < 4; ++j) {
                const int tl = tq * 32 + j * 8;
                short8 o;
#pragma unroll
                for (int e = 0; e < 8; ++e)
                    o[e] = (short)f2b(epi[tl + e][d]);
                const int chunkidx = (tloc0 + tl) >> 3;
                const int pos = (chunkidx & ~7) | ((chunkidx & 7) ^ (d & 7));
                *(short8*)(op + pos * 8) = o;
            }
        }
    }
}

// ---------------------------------------------------------------------------
// attn_mfma (proven config): QBLK=64, 4 waves, grid 1280 (16 bh x 80),
// XCD-pinned, big-bt first, <=8 tiles/chunk. K/V double-buffered gl2lds
// staging; s_setprio around MFMA clusters. Partial Y slices stored as BF16.
// ---------------------------------------------------------------------------
__global__ __launch_bounds__(256) void attn_mfma(
    const unsigned short* __restrict__ Qsb, const unsigned short* __restrict__ Ksb,
    const unsigned short* __restrict__ Vtb,
    unsigned short* __restrict__ Ypb, float* __restrict__ Dpart)
{
    __shared__ __align__(16) char smem[40960];
    char* PsB = smem + 32768;

    const int wg = blockIdx.x;
    const int xcd = wg & 7;
    const int slot = wg >> 3;
    const int bh = (slot < 80) ? xcd : 8 + xcd;
    const int rem = (slot < 80) ? slot : slot - 80;
    const int rr = 79 - rem;
    int bt, sc;
    if (rr < 8)       { bt = rr; sc = 0; }
    else if (rr < 24) { const int q = rr - 8;  bt = 8 + (q >> 1);  sc = q & 1; }
    else if (rr < 48) { const int q = rr - 24; bt = 16 + q / 3;    sc = q % 3; }
    else              { const int q = rr - 48; bt = 24 + (q >> 2); sc = q & 3; }
    const int st0 = sc * SC_;
    const int st1 = min(st0 + SC_ - 1, bt);

    const int tid = threadIdx.x;
    const int wave = tid >> 6;
    const int lane = tid & 63;
    const int l15 = lane & 15;
    const int lhi = lane >> 4;
    const int b = bh >> 3, h = bh & 7;
    const int t0 = bt * 64;

    const int qrow = t0 + wave * 16 + l15;
    const unsigned short* qpp = Qsb + ((size_t)bh * T_ + qrow) * 64 + lhi * 8;
    short8 qf[2];
    qf[0] = *(const short8*)(qpp);
    qf[1] = *(const short8*)(qpp + 32);

    f32x4 accY[4];
#pragma unroll
    for (int n = 0; n < 4; ++n) accY[n] = (f32x4){0.f, 0.f, 0.f, 0.f};
    float den[4] = {0.f, 0.f, 0.f, 0.f};

    const int kchunk = lhi * 16;
    const int rsw = (l15 & 7) << 4;
    const int srow = tid >> 3;
    const int schunk = tid & 7;

    // prologue: stage tile st0 into buffer 0
#pragma unroll
    for (int p = 0; p < 2; ++p) {
        const int row = p * 32 + srow;
        gl2lds16(Ksb + ((size_t)bh * T_ + st0 * 64 + row) * 64 + schunk * 8,
                 smem + p * 4096 + wave * 1024);
        gl2lds16(Vtb + ((size_t)bh * 64 + row) * T_ + st0 * 64 + schunk * 8,
                 smem + 8192 + p * 4096 + wave * 1024);
    }

    for (int st = st0; st <= st1; ++st) {
        __syncthreads();
        if (st < st1) {
            char* dst = smem + (((st - st0) + 1) & 1) * 16384;
            const int s1 = (st + 1) * 64;
#pragma unroll
            for (int p = 0; p < 2; ++p) {
                const int row = p * 32 + srow;
                gl2lds16(Ksb + ((size_t)bh * T_ + s1 + row) * 64 + schunk * 8,
                         dst + p * 4096 + wave * 1024);
                gl2lds16(Vtb + ((size_t)bh * 64 + row) * T_ + s1 + schunk * 8,
                         dst + 8192 + p * 4096 + wave * 1024);
            }
        }
        const char* KsB = smem + ((st - st0) & 1) * 16384;
        const char* VtB = KsB + 8192;

        f32x4 accS[4];
#pragma unroll
        for (int n = 0; n < 4; ++n) accS[n] = (f32x4){0.f, 0.f, 0.f, 0.f};
        __builtin_amdgcn_s_setprio(1);
#pragma unroll
        for (int n = 0; n < 4; ++n) {
#pragma unroll
            for (int kk = 0; kk < 2; ++kk) {
                short8 bf = *(const short8*)(KsB + (n * 16 + l15) * 128 + ((kk * 64 + kchunk) ^ rsw));
                accS[n] = __builtin_amdgcn_mfma_f32_16x16x32_bf16(qf[kk], bf, accS[n], 0, 0, 0);
            }
        }
        __builtin_amdgcn_s_setprio(0);

        const bool last = (st == bt);
        char* PsW = PsB + wave * 2048;
#pragma unroll
        for (int n = 0; n < 4; ++n) {
#pragma unroll
            for (int r = 0; r < 4; ++r) {
                const float a = accS[n][r];
                float p = a * a;
                if (last)
                    p = ((n * 16 + l15) <= wave * 16 + lhi * 4 + r) ? p : 0.f;
                den[r] += p;
                const int prow = lhi * 4 + r;
                *(unsigned short*)(PsW + prow * 128 + ((2 * (n * 16 + l15)) ^ ((prow & 7) << 4))) = f2b(p);
            }
        }

        short8 pa[2];
#pragma unroll
        for (int kk = 0; kk < 2; ++kk)
            pa[kk] = *(const short8*)(PsW + l15 * 128 + ((kk * 64 + kchunk) ^ rsw));
        __builtin_amdgcn_s_setprio(1);
#pragma unroll
        for (int n = 0; n < 4; ++n) {
#pragma unroll
            for (int kk = 0; kk < 2; ++kk) {
                short8 vb = *(const short8*)(VtB + (n * 16 + l15) * 128 + ((kk * 64 + kchunk) ^ rsw));
                accY[n] = __builtin_amdgcn_mfma_f32_16x16x32_bf16(pa[kk], vb, accY[n], 0, 0, 0);
            }
        }
        __builtin_amdgcn_s_setprio(0);
    }

#pragma unroll
    for (int r = 0; r < 4; ++r) {
        den[r] += __shfl_xor(den[r], 1, 64);
        den[r] += __shfl_xor(den[r], 2, 64);
        den[r] += __shfl_xor(den[r], 4, 64);
        den[r] += __shfl_xor(den[r], 8, 64);
    }

    unsigned short* Ybase = Ypb + (size_t)sc * MC_;
    float* Dbase = Dpart + (size_t)sc * BHT_;
#pragma unroll
    for (int r = 0; r < 4; ++r) {
        const int t = t0 + wave * 16 + lhi * 4 + r;
        if (l15 == 0)
            Dbase[(size_t)bh * T_ + t] = den[r];
        unsigned short* yo = Ybase + (size_t)(b * T_ + t) * (H_ * D_) + h * 64 + l15;
#pragma unroll
        for (int n = 0; n < 4; ++n)
            yo[n * 16] = f2b(accY[n][r]);
    }
}

// ---------------------------------------------------------------------------
// gemm2_fused: out = normalize(Ypb, Dpart) @ w_proj^T.
// A-tile built on the fly: per K-step ks (= head h), sum nsc bf16 slices in
// fp32, scale by invden[h][row], pack bf16, ds_write (swizzled). Slice loads
// issued BEFORE the MFMA cluster (latency hidden under compute). nsc is
// uniform per block (64-row tile within one 512-t bucket).
// B staged via gl2lds. LDS: [A0 8K][B0 16K][A1 8K][B1 16K][invden 2K].
// ---------------------------------------------------------------------------
__global__ __launch_bounds__(256) void gemm2_fused(
    const unsigned short* __restrict__ Ypb, const float* __restrict__ Dpart,
    const unsigned short* __restrict__ Bt, float* __restrict__ C)
{
    __shared__ __align__(16) char smem[51200];
    float* invden = (float*)(smem + 49152);   // [h*64+row]

    const int tid = threadIdx.x;
    const int wave = tid >> 6, lane = tid & 63;
    const int l15 = lane & 15, lhi = lane >> 4;
    const int wr = wave >> 1, wc = wave & 1;
    const int bm = blockIdx.y * 64, bn = blockIdx.x * 128;
    const int b = bm >> 11, t0 = bm & 2047;
    const int nsc = (t0 >> 9) + 1;

    // invden[h][row] (512 entries, 2 per thread)
#pragma unroll
    for (int q = 0; q < 2; ++q) {
        const int idx = q * 256 + tid;
        const int h = idx >> 6, row = idx & 63;
        float d = 0.f;
        for (int s = 0; s < nsc; ++s)
            d += Dpart[(size_t)s * BHT_ + (size_t)(b * 8 + h) * T_ + t0 + row];
        invden[idx] = 1.0f / fmaxf(d, 1e-6f);
    }

    const unsigned short* Brow = Bt + (size_t)bn * C_;
    const int sw = (l15 & 7) << 4;
    const int srow = tid >> 3;            // 0..31 (+32 for p=1)
    const int schunk = tid & 7;

    f32x4 acc[2][4];
#pragma unroll
    for (int i = 0; i < 2; ++i)
#pragma unroll
        for (int j = 0; j < 4; ++j) acc[i][j] = (f32x4){0.f, 0.f, 0.f, 0.f};

    // B0 prefetch (async)
#pragma unroll
    for (int p = 0; p < 4; ++p) {
        const int row = p * 32 + srow;
        gl2lds16(Brow + (size_t)row * C_ + schunk * 8, smem + 8192 + p * 4096 + wave * 1024);
    }
    __syncthreads();   // invden visible

    // A0 reg-stage (h = 0)
#pragma unroll
    for (int p = 0; p < 2; ++p) {
        const int row = p * 32 + srow;
        float a8[8] = {0.f, 0.f, 0.f, 0.f, 0.f, 0.f, 0.f, 0.f};
#pragma unroll
        for (int s = 0; s < 4; ++s) {
            if (s < nsc) {
                short8 v = *(const short8*)(Ypb + (size_t)s * MC_ + (size_t)(bm + row) * 512 + schunk * 8);
#pragma unroll
                for (int j = 0; j < 8; ++j) a8[j] += b2f((unsigned short)v[j]);
            }
        }
        const float iv = invden[row];
#pragma unroll
        for (int j = 0; j < 8; ++j) a8[j] *= iv;
        short8 o = pack8(*(float4*)&a8[0], *(float4*)&a8[4]);
        *(short8*)(smem + row * 128 + ((schunk << 4) ^ ((row & 7) << 4))) = o;
    }

    for (int ks = 0; ks < 8; ++ks) {
        __syncthreads();   // A(ks), B(ks) ready; other buffer free
        short8 vv[2][4];
        const bool have = (ks < 7);
        if (have) {
            char* dst = smem + ((ks + 1) & 1) * 24576;
            const int k1 = (ks + 1) * 64;
#pragma unroll
            for (int p = 0; p < 4; ++p) {
                const int row = p * 32 + srow;
                gl2lds16(Brow + (size_t)row * C_ + k1 + schunk * 8, dst + 8192 + p * 4096 + wave * 1024);
            }
            // issue A(ks+1) slice loads early (results consumed after MFMA)
#pragma unroll
            for (int p = 0; p < 2; ++p) {
                const int row = p * 32 + srow;
#pragma unroll
                for (int s = 0; s < 4; ++s) {
                    if (s < nsc)
                        vv[p][s] = *(const short8*)(Ypb + (size_t)s * MC_ + (size_t)(bm + row) * 512 + k1 + schunk * 8);
                    else
                        vv[p][s] = (short8){0,0,0,0,0,0,0,0};
                }
            }
        }

        const char* AsB = smem + (ks & 1) * 24576;
        const char* BsB = AsB + 8192;

        short8 af[2][2];
#pragma unroll
        for (int mi = 0; mi < 2; ++mi) {
            const int row = wr * 32 + mi * 16 + l15;
#pragma unroll
            for (int kk = 0; kk < 2; ++kk)
                af[mi][kk] = *(const short8*)(AsB + row * 128 + ((kk * 64 + lhi * 16) ^ sw));
        }
#pragma unroll
        for (int ni = 0; ni < 4; ++ni) {
            const int row = wc * 64 + ni * 16 + l15;
            short8 bf0 = *(const short8*)(BsB + row * 128 + ((lhi * 16) ^ sw));
            short8 bf1 = *(const short8*)(BsB + row * 128 + ((64 + lhi * 16) ^ sw));
#pragma unroll
            for (int mi = 0; mi < 2; ++mi) {
                acc[mi][ni] = __builtin_amdgcn_mfma_f32_16x16x32_bf16(af[mi][0], bf0, acc[mi][ni], 0, 0, 0);
                acc[mi][ni] = __builtin_amdgcn_mfma_f32_16x16x32_bf16(af[mi][1], bf1, acc[mi][ni], 0, 0, 0);
            }
        }

        if (have) {
            // finish A(ks+1): sum, scale, pack, ds_write (swizzled)
            char* dst = smem + ((ks + 1) & 1) * 24576;
            const int h1 = ks + 1;
#pragma unroll
            for (int p = 0; p < 2; ++p) {
                const int row = p * 32 + srow;
                float a8[8] = {0.f, 0.f, 0.f, 0.f, 0.f, 0.f, 0.f, 0.f};
#pragma unroll
                for (int s = 0; s < 4; ++s) {
#pragma unroll
                    for (int j = 0; j < 8; ++j) a8[j] += b2f((unsigned short)vv[p][s][j]);
                }
                const float iv = invden[h1 * 64 + row];
#pragma unroll
                for (int j = 0; j < 8; ++j) a8[j] *= iv;
                short8 o = pack8(*(float4*)&a8[0], *(float4*)&a8[4]);
                *(short8*)(dst + row * 128 + ((schunk << 4) ^ ((row & 7) << 4))) = o;
            }
        }
    }

#pragma unroll
    for (int mi = 0; mi < 2; ++mi) {
        const int gm = bm + wr * 32 + mi * 16 + lhi * 4;
#pragma unroll
        for (int r = 0; r < 4; ++r) {
            float* crow = C + (size_t)(gm + r) * C_;
#pragma unroll
            for (int ni = 0; ni < 4; ++ni) {
                const int gn = bn + wc * 64 + ni * 16 + l15;
                crow[gn] = acc[mi][ni][r];
            }
        }
    }
}

// ---------------------------------------------------------------------------
extern "C" void kernel_launch(void* const* d_in, const int* in_sizes, int n_in,
                              void* d_out, int out_size, void* d_ws, size_t ws_size,
                              hipStream_t stream)
{
    const float* x      = (const float*)d_in[0];
    const float* w_attn = (const float*)d_in[1];
    const float* w_proj = (const float*)d_in[2];
    float* out = (float*)d_out;

    // workspace (~35 MB of ~256 MB), no aliasing:
    char* p = (char*)d_ws;
    float2* sincos = (float2*)p;               p += (size_t)T_ * 32 * 8;       // 512 KB
    float* g       = (float*)p;                p += (size_t)BHT_ * 4;          // 128 KB
    float* Lg      = (float*)p;                p += (size_t)BHT_ * 4;          // 128 KB
    float* Dpart   = (float*)p;                p += (size_t)4 * BHT_ * 4;      // 512 KB
    unsigned short* xb  = (unsigned short*)p;  p += (size_t)MC_ * 2;           // 4 MB
    unsigned short* Bt1 = (unsigned short*)p;  p += (size_t)N1_ * C_ * 2;      // 1.5 MB
    unsigned short* Bt2 = (unsigned short*)p;  p += (size_t)C_ * C_ * 2;       // 0.5 MB
    unsigned short* Qsb = (unsigned short*)p;  p += (size_t)BHT_ * 64 * 2;     // 4 MB
    unsigned short* Ksb = (unsigned short*)p;  p += (size_t)BHT_ * 64 * 2;     // 4 MB
    unsigned short* Vtb = (unsigned short*)p;  p += (size_t)BHT_ * 64 * 2;     // 4 MB
    unsigned short* Ypb = (unsigned short*)p;                                  // 16 MB

    const int M = B_ * T_;      // 4096

    // 0) packs + sincos table + gate GEMV
    pack_inputs<<<1416, 256, 0, stream>>>(x, w_attn, w_proj, xb, Bt1, Bt2, sincos, g);

    // 1) gate log-sigmoid + cumsum -> Lg
    gate_cumsum<<<B_ * H_, 256, 0, stream>>>(g, Lg);

    // 2) fused qkv GEMM + RoPE/prescale/transpose epilogue -> Qsb, Ksb, Vtb
    gemm_fused<<<dim3(N1_ / 128, M / 128), 256, 0, stream>>>(
        xb, Bt1, Lg, sincos, Qsb, Ksb, Vtb);

    // 3) split-s attention (QBLK=64), bf16 partial slices
    attn_mfma<<<NBLK_, 256, 0, stream>>>(Qsb, Ksb, Vtb, Ypb, Dpart);

    // 4) out = normalize(Ypb) @ w_proj  (fused; 64x128 tiles, 256 blocks)
    gemm2_fused<<<dim3(C_ / 128, M / 64), 256, 0, stream>>>(
        Ypb, Dpart, Bt2, out);
}

// Round 20
// 76.518 us; speedup vs baseline: 1.0357x; 1.0357x over previous
//
#include <hip/hip_runtime.h>
#include <hip/hip_bf16.h>
#include <math.h>

// Problem constants (fixed by setup_inputs)
constexpr int B_ = 2, T_ = 2048, C_ = 512, H_ = 8, D_ = 64;
constexpr int QKVG_ = 3 * H_ * D_ + H_;   // 1544 (w_attn row stride)
constexpr float GATE_BIAS_ = 6.906768f;
constexpr int N1_ = 1536;                 // gemm1 N (Q,K,V only; gate separate)
constexpr int SC_ = 8;                    // s-tiles per attn chunk
constexpr int NBLK_ = 1280;               // attn blocks (16 bh x 80)
constexpr int MC_ = 4096 * 512;           // 2,097,152
constexpr int BHT_ = B_ * H_ * T_;        // 32,768

typedef __attribute__((ext_vector_type(8))) short short8;
typedef __attribute__((ext_vector_type(4))) float f32x4;

// hardware RNE f32->bf16 (compiler fuses pairs into v_cvt_pk_bf16_f32)
__device__ __forceinline__ unsigned short f2b(float f) {
    union { __hip_bfloat16 h; unsigned short u; } cv;
    cv.h = __float2bfloat16(f);
    return cv.u;
}
__device__ __forceinline__ float b2f(unsigned short u) {
    return __uint_as_float((unsigned int)u << 16);
}
__device__ __forceinline__ short8 pack8(float4 a, float4 b) {
    short8 r;
    r[0] = (short)f2b(a.x); r[1] = (short)f2b(a.y);
    r[2] = (short)f2b(a.z); r[3] = (short)f2b(a.w);
    r[4] = (short)f2b(b.x); r[5] = (short)f2b(b.y);
    r[6] = (short)f2b(b.z); r[7] = (short)f2b(b.w);
    return r;
}

// async global->LDS, 16 B/lane
__device__ __forceinline__ void gl2lds16(const unsigned short* g, void* lds_base) {
    __builtin_amdgcn_global_load_lds(
        (const __attribute__((address_space(1))) unsigned int*)g,
        (__attribute__((address_space(3))) unsigned int*)lds_base, 16, 0, 0);
}

// ---------------------------------------------------------------------------
// pack_inputs: [0,1024) x->xb (pre-swz) | [1024,1216) w_attn->Bt1 (24x8) |
// [1216,1280) w_proj->Bt2 (8x8) | [1280,1288) sincos table | [1288,1416) gate GEMV
// ---------------------------------------------------------------------------
__device__ __forceinline__ void packT_body(
    const float* __restrict__ W, unsigned short* __restrict__ Bt,
    int K, int N, int ldW, int nt, int kt, int tid, float (*Ws)[65])
{
    {
        const int r = tid >> 2;
        const int c0 = (tid & 3) * 16;
#pragma unroll
        for (int j = 0; j < 16; ++j) {
            const int n = nt + c0 + j;
            Ws[r][c0 + j] = (n < N) ? W[(size_t)(kt + r) * ldW + n] : 0.f;
        }
    }
    __syncthreads();
    {
        const int d = tid >> 2;
        const int cc = tid & 3;
        const int kc = cc * 16;
        short8 o0, o1;
#pragma unroll
        for (int j = 0; j < 8; ++j) o0[j] = (short)f2b(Ws[kc + j][d]);
#pragma unroll
        for (int j = 0; j < 8; ++j) o1[j] = (short)f2b(Ws[kc + 8 + j][d]);
        const int row = nt + d;
        unsigned short* op = Bt + (size_t)row * K + kt;
        *(short8*)(op + ((2 * cc) ^ (row & 7)) * 8)     = o0;
        *(short8*)(op + ((2 * cc + 1) ^ (row & 7)) * 8) = o1;
    }
}

__global__ __launch_bounds__(256) void pack_inputs(
    const float* __restrict__ x, const float* __restrict__ w_attn,
    const float* __restrict__ w_proj, unsigned short* __restrict__ xb,
    unsigned short* __restrict__ Bt1, unsigned short* __restrict__ Bt2,
    float2* __restrict__ sincos, float* __restrict__ g)
{
    __shared__ float SM[64 * 65];
    float (*Ws)[65] = (float(*)[65])SM;
    const int bid = blockIdx.x;
    const int tid = threadIdx.x;
    if (bid < 1024) {
        const int i = bid * 256 + tid;
        float4 f0 = *(const float4*)(x + (size_t)i * 8);
        float4 f1 = *(const float4*)(x + (size_t)i * 8 + 4);
        const int row = i >> 6;
        const int ic = i & 63;
        const int swc = (ic & ~7) | ((ic & 7) ^ (row & 7));
        *(short8*)(xb + (size_t)row * 512 + swc * 8) = pack8(f0, f1);
    } else if (bid < 1216) {
        const int q = bid - 1024;
        packT_body(w_attn, Bt1, C_, N1_, QKVG_, (q % 24) * 64, (q / 24) * 64, tid, Ws);
    } else if (bid < 1280) {
        const int q = bid - 1216;
        packT_body(w_proj, Bt2, H_ * D_, C_, C_, (q & 7) * 64, (q >> 3) * 64, tid, Ws);
    } else if (bid < 1288) {
        const int t = (bid - 1280) * 256 + tid;
        float2* op = sincos + (size_t)t * 32;
#pragma unroll
        for (int i = 0; i < 32; ++i) {
            const float div = 6.2831853071795864f * exp2f((float)i * (-11.0f / 32.0f));
            const float ang = (float)t * div;
            op[i] = make_float2(cosf(ang), sinf(ang));
        }
    } else {
        // gate GEMV: g[bh][t] = x[m] . w_attn[:,1536+h]
        const int q = bid - 1288;
        float* LDSw = SM;                      // [512][8]
        {
            const int k = tid * 2;
#pragma unroll
            for (int kk = 0; kk < 2; ++kk) {
                const float* wp = w_attn + (size_t)(k + kk) * QKVG_ + 1536;
                float4 wa = *(const float4*)wp;
                float4 wb = *(const float4*)(wp + 4);
                float* dst = LDSw + (k + kk) * 8;
                *(float4*)dst = wa;
                *(float4*)(dst + 4) = wb;
            }
        }
        __syncthreads();
        const int m = q * 32 + (tid >> 3);
        const int h = tid & 7;
        const float* xrow = x + (size_t)m * C_;
        float s = 0.f;
#pragma unroll 4
        for (int k0 = 0; k0 < 512; k0 += 4) {
            float4 xv = *(const float4*)(xrow + k0);
            s += xv.x * LDSw[(k0 + 0) * 8 + h] + xv.y * LDSw[(k0 + 1) * 8 + h]
               + xv.z * LDSw[(k0 + 2) * 8 + h] + xv.w * LDSw[(k0 + 3) * 8 + h];
        }
        const int b = m >> 11, t = m & 2047;
        g[(size_t)(b * 8 + h) * T_ + t] = s;
    }
}

// ---------------------------------------------------------------------------
// gate_cumsum: one block per (b,h): log-sigmoid(g+bias) + block inclusive scan
// ---------------------------------------------------------------------------
__global__ __launch_bounds__(256) void gate_cumsum(
    const float* __restrict__ g, float* __restrict__ Lg)
{
    __shared__ float wsum[4];
    const int bh = blockIdx.x;
    const int tid = threadIdx.x;
    const int lane = tid & 63, wv = tid >> 6;

    const float* gp = g + (size_t)bh * T_ + tid * 8;
    float v[8];
    float s = 0.f;
#pragma unroll
    for (int j = 0; j < 8; ++j) {
        const float z = gp[j] + GATE_BIAS_;
        const float lg = (z > 0.f) ? -log1pf(expf(-z)) : (z - log1pf(expf(z)));
        s += lg;
        v[j] = s;
    }
    float ssum = s;
#pragma unroll
    for (int off = 1; off < 64; off <<= 1) {
        float n = __shfl_up(ssum, off, 64);
        if (lane >= off) ssum += n;
    }
    if (lane == 63) wsum[wv] = ssum;
    __syncthreads();
    float base = ssum - s;
#pragma unroll
    for (int w = 0; w < 3; ++w)
        base += (w < wv) ? wsum[w] : 0.f;

    float* op = Lg + (size_t)bh * T_ + tid * 8;
#pragma unroll
    for (int j = 0; j < 8; ++j) op[j] = v[j] + base;
}

// ---------------------------------------------------------------------------
// gemm_fused: qkv = xb @ Bt1^T (MFMA, N=1536), double-buffered gl2lds staging,
// fused epilogue -> Qsb / Ksb(swz) / Vtb(transposed, swz)
// ---------------------------------------------------------------------------
__global__ __launch_bounds__(256) void gemm_fused(
    const unsigned short* __restrict__ A, const unsigned short* __restrict__ Bt,
    const float* __restrict__ Lg, const float2* __restrict__ sincos,
    unsigned short* __restrict__ Qsb, unsigned short* __restrict__ Ksb,
    unsigned short* __restrict__ Vtb)
{
    __shared__ __align__(16) char smem[65536];
    float (*epi)[65] = (float(*)[65])smem;

    const int tid = threadIdx.x;
    const int wave = tid >> 6, lane = tid & 63;
    const int l15 = lane & 15, lhi = lane >> 4;
    const int wr = wave >> 1, wc = wave & 1;
    const int bm = blockIdx.y * 128, bn = blockIdx.x * 128;

    f32x4 acc[4][4];
#pragma unroll
    for (int i = 0; i < 4; ++i)
#pragma unroll
        for (int j = 0; j < 4; ++j) acc[i][j] = (f32x4){0.f, 0.f, 0.f, 0.f};

    const unsigned short* Arow = A + (size_t)bm * C_;
    const unsigned short* Brow = Bt + (size_t)bn * C_;
    const int sw = (l15 & 7) << 4;
    const int srow = tid >> 3;
    const int schunk = tid & 7;

    // prologue: stage k-step 0 into buffer 0
#pragma unroll
    for (int p = 0; p < 4; ++p) {
        const int row = p * 32 + srow;
        const size_t goff = (size_t)row * C_ + schunk * 8;
        gl2lds16(Arow + goff, smem + p * 4096 + wave * 1024);
        gl2lds16(Brow + goff, smem + 16384 + p * 4096 + wave * 1024);
    }

    for (int ks = 0; ks < 8; ++ks) {
        __syncthreads();
        if (ks < 7) {
            char* dst = smem + ((ks + 1) & 1) * 32768;
            const int k1 = (ks + 1) * 64;
#pragma unroll
            for (int p = 0; p < 4; ++p) {
                const int row = p * 32 + srow;
                const size_t goff = (size_t)row * C_ + k1 + schunk * 8;
                gl2lds16(Arow + goff, dst + p * 4096 + wave * 1024);
                gl2lds16(Brow + goff, dst + 16384 + p * 4096 + wave * 1024);
            }
        }
        const char* AsB = smem + (ks & 1) * 32768;
        const char* BsB = AsB + 16384;

        short8 af[4][2];
#pragma unroll
        for (int mi = 0; mi < 4; ++mi) {
            const int row = wr * 64 + mi * 16 + l15;
#pragma unroll
            for (int kk = 0; kk < 2; ++kk)
                af[mi][kk] = *(const short8*)(AsB + row * 128 + ((kk * 64 + lhi * 16) ^ sw));
        }
#pragma unroll
        for (int ni = 0; ni < 4; ++ni) {
            const int row = wc * 64 + ni * 16 + l15;
            short8 bf0 = *(const short8*)(BsB + row * 128 + ((lhi * 16) ^ sw));
            short8 bf1 = *(const short8*)(BsB + row * 128 + ((64 + lhi * 16) ^ sw));
#pragma unroll
            for (int mi = 0; mi < 4; ++mi) {
                acc[mi][ni] = __builtin_amdgcn_mfma_f32_16x16x32_bf16(af[mi][0], bf0, acc[mi][ni], 0, 0, 0);
                acc[mi][ni] = __builtin_amdgcn_mfma_f32_16x16x32_bf16(af[mi][1], bf1, acc[mi][ni], 0, 0, 0);
            }
        }
    }

    // -------- fused epilogue --------
    const int rid = bn >> 9;              // 0 Q, 1 K, 2 V
    const int b = bm >> 11;
    const int tloc0 = bm & 2047;

#pragma unroll
    for (int hc = 0; hc < 2; ++hc) {
        __syncthreads();
        if (wc == hc) {
#pragma unroll
            for (int mi = 0; mi < 4; ++mi)
#pragma unroll
                for (int ni = 0; ni < 4; ++ni)
#pragma unroll
                    for (int r = 0; r < 4; ++r)
                        epi[wr * 64 + mi * 16 + lhi * 4 + r][ni * 16 + l15] = acc[mi][ni][r];
        }
        __syncthreads();
        const int h = ((bn & 511) >> 6) + hc;
        const int bh = b * 8 + h;
        if (rid < 2) {
            const int row = tid >> 1;
            const int c0 = (tid & 1) * 32;
            const int t = tloc0 + row;
            const float Lt = Lg[(size_t)bh * T_ + t];
            const float scl = (rid == 0) ? (__expf(0.5f * Lt) * 0.125f)
                                         : __expf(-0.5f * Lt);
            float vb[32];
#pragma unroll
            for (int j = 0; j < 32; ++j) vb[j] = epi[row][c0 + j];
            const float2* sct = sincos + (size_t)t * 32 + (c0 >> 1);
#pragma unroll
            for (int p = 0; p < 16; ++p) {
                const float2 cssn = sct[p];
                const float x1 = vb[2 * p], x2 = vb[2 * p + 1];
                vb[2 * p]     = (x1 * cssn.x - x2 * cssn.y) * scl;
                vb[2 * p + 1] = (x2 * cssn.x + x1 * cssn.y) * scl;
            }
            unsigned short* op = ((rid == 0) ? Qsb : Ksb) + ((size_t)bh * T_ + t) * 64;
#pragma unroll
            for (int j = 0; j < 4; ++j) {
                short8 o = pack8(*(float4*)&vb[j * 8], *(float4*)&vb[j * 8 + 4]);
                const int chunk = (c0 >> 3) + j;
                const int pos = (rid == 0) ? chunk : (chunk ^ (t & 7));
                *(short8*)(op + pos * 8) = o;
            }
        } else {
            const int d = tid >> 2;
            const int tq = tid & 3;
            unsigned short* op = Vtb + ((size_t)(bh * 64 + d)) * T_;
#pragma unroll
            for (int j = 0; j < 4; ++j) {
                const int tl = tq * 32 + j * 8;
                short8 o;
#pragma unroll
                for (int e = 0; e < 8; ++e)
                    o[e] = (short)f2b(epi[tl + e][d]);
                const int chunkidx = (tloc0 + tl) >> 3;
                const int pos = (chunkidx & ~7) | ((chunkidx & 7) ^ (d & 7));
                *(short8*)(op + pos * 8) = o;
            }
        }
    }
}

// ---------------------------------------------------------------------------
// gemm_bf16 (gemm2): C = A @ Bt^T, tile 64x128 (grid 256 blocks),
// pre-swizzled operands, double-buffered gl2lds staging.
// ---------------------------------------------------------------------------
__global__ __launch_bounds__(256) void gemm_bf16(
    const unsigned short* __restrict__ A, const unsigned short* __restrict__ Bt,
    float* __restrict__ C, int M, int N, int K)
{
    __shared__ __align__(16) char smem[49152];

    const int tid = threadIdx.x;
    const int wave = tid >> 6, lane = tid & 63;
    const int l15 = lane & 15, lhi = lane >> 4;
    const int wr = wave >> 1, wc = wave & 1;
    const int bm = blockIdx.y * 64, bn = blockIdx.x * 128;

    f32x4 acc[2][4];
#pragma unroll
    for (int i = 0; i < 2; ++i)
#pragma unroll
        for (int j = 0; j < 4; ++j) acc[i][j] = (f32x4){0.f, 0.f, 0.f, 0.f};

    const unsigned short* Arow = A + (size_t)bm * K;
    const unsigned short* Brow = Bt + (size_t)bn * K;
    const int sw = (l15 & 7) << 4;
    const int srow = tid >> 3;
    const int schunk = tid & 7;
    const int nks = K >> 6;

    // prologue
#pragma unroll
    for (int p = 0; p < 2; ++p) {
        const int row = p * 32 + srow;
        gl2lds16(Arow + (size_t)row * K + schunk * 8, smem + p * 4096 + wave * 1024);
    }
#pragma unroll
    for (int p = 0; p < 4; ++p) {
        const int row = p * 32 + srow;
        gl2lds16(Brow + (size_t)row * K + schunk * 8, smem + 8192 + p * 4096 + wave * 1024);
    }

    for (int ks = 0; ks < nks; ++ks) {
        __syncthreads();
        if (ks + 1 < nks) {
            char* dst = smem + ((ks + 1) & 1) * 24576;
            const int k1 = (ks + 1) * 64;
#pragma unroll
            for (int p = 0; p < 2; ++p) {
                const int row = p * 32 + srow;
                gl2lds16(Arow + (size_t)row * K + k1 + schunk * 8, dst + p * 4096 + wave * 1024);
            }
#pragma unroll
            for (int p = 0; p < 4; ++p) {
                const int row = p * 32 + srow;
                gl2lds16(Brow + (size_t)row * K + k1 + schunk * 8, dst + 8192 + p * 4096 + wave * 1024);
            }
        }
        const char* AsB = smem + (ks & 1) * 24576;
        const char* BsB = AsB + 8192;

        short8 af[2][2];
#pragma unroll
        for (int mi = 0; mi < 2; ++mi) {
            const int row = wr * 32 + mi * 16 + l15;
#pragma unroll
            for (int kk = 0; kk < 2; ++kk)
                af[mi][kk] = *(const short8*)(AsB + row * 128 + ((kk * 64 + lhi * 16) ^ sw));
        }
#pragma unroll
        for (int ni = 0; ni < 4; ++ni) {
            const int row = wc * 64 + ni * 16 + l15;
            short8 bf0 = *(const short8*)(BsB + row * 128 + ((lhi * 16) ^ sw));
            short8 bf1 = *(const short8*)(BsB + row * 128 + ((64 + lhi * 16) ^ sw));
#pragma unroll
            for (int mi = 0; mi < 2; ++mi) {
                acc[mi][ni] = __builtin_amdgcn_mfma_f32_16x16x32_bf16(af[mi][0], bf0, acc[mi][ni], 0, 0, 0);
                acc[mi][ni] = __builtin_amdgcn_mfma_f32_16x16x32_bf16(af[mi][1], bf1, acc[mi][ni], 0, 0, 0);
            }
        }
    }

#pragma unroll
    for (int mi = 0; mi < 2; ++mi) {
        const int gm = bm + wr * 32 + mi * 16 + lhi * 4;
#pragma unroll
        for (int r = 0; r < 4; ++r) {
            float* crow = C + (size_t)(gm + r) * N;
#pragma unroll
            for (int ni = 0; ni < 4; ++ni) {
                const int gn = bn + wc * 64 + ni * 16 + l15;
                if (gn < N) crow[gn] = acc[mi][ni][r];
            }
        }
    }
}

// ---------------------------------------------------------------------------
// attn_mfma (proven config): QBLK=64, 4 waves, grid 1280 (16 bh x 80),
// XCD-pinned, big-bt first, <=8 tiles/chunk. K/V double-buffered gl2lds
// staging; s_setprio around MFMA clusters. Partial Y slices stored as BF16.
// ---------------------------------------------------------------------------
__global__ __launch_bounds__(256) void attn_mfma(
    const unsigned short* __restrict__ Qsb, const unsigned short* __restrict__ Ksb,
    const unsigned short* __restrict__ Vtb,
    unsigned short* __restrict__ Ypb, float* __restrict__ Dpart)
{
    __shared__ __align__(16) char smem[40960];
    char* PsB = smem + 32768;

    const int wg = blockIdx.x;
    const int xcd = wg & 7;
    const int slot = wg >> 3;
    const int bh = (slot < 80) ? xcd : 8 + xcd;
    const int rem = (slot < 80) ? slot : slot - 80;
    const int rr = 79 - rem;
    int bt, sc;
    if (rr < 8)       { bt = rr; sc = 0; }
    else if (rr < 24) { const int q = rr - 8;  bt = 8 + (q >> 1);  sc = q & 1; }
    else if (rr < 48) { const int q = rr - 24; bt = 16 + q / 3;    sc = q % 3; }
    else              { const int q = rr - 48; bt = 24 + (q >> 2); sc = q & 3; }
    const int st0 = sc * SC_;
    const int st1 = min(st0 + SC_ - 1, bt);

    const int tid = threadIdx.x;
    const int wave = tid >> 6;
    const int lane = tid & 63;
    const int l15 = lane & 15;
    const int lhi = lane >> 4;
    const int b = bh >> 3, h = bh & 7;
    const int t0 = bt * 64;

    const int qrow = t0 + wave * 16 + l15;
    const unsigned short* qpp = Qsb + ((size_t)bh * T_ + qrow) * 64 + lhi * 8;
    short8 qf[2];
    qf[0] = *(const short8*)(qpp);
    qf[1] = *(const short8*)(qpp + 32);

    f32x4 accY[4];
#pragma unroll
    for (int n = 0; n < 4; ++n) accY[n] = (f32x4){0.f, 0.f, 0.f, 0.f};
    float den[4] = {0.f, 0.f, 0.f, 0.f};

    const int kchunk = lhi * 16;
    const int rsw = (l15 & 7) << 4;
    const int srow = tid >> 3;
    const int schunk = tid & 7;

    // prologue: stage tile st0 into buffer 0
#pragma unroll
    for (int p = 0; p < 2; ++p) {
        const int row = p * 32 + srow;
        gl2lds16(Ksb + ((size_t)bh * T_ + st0 * 64 + row) * 64 + schunk * 8,
                 smem + p * 4096 + wave * 1024);
        gl2lds16(Vtb + ((size_t)bh * 64 + row) * T_ + st0 * 64 + schunk * 8,
                 smem + 8192 + p * 4096 + wave * 1024);
    }

    for (int st = st0; st <= st1; ++st) {
        __syncthreads();
        if (st < st1) {
            char* dst = smem + (((st - st0) + 1) & 1) * 16384;
            const int s1 = (st + 1) * 64;
#pragma unroll
            for (int p = 0; p < 2; ++p) {
                const int row = p * 32 + srow;
                gl2lds16(Ksb + ((size_t)bh * T_ + s1 + row) * 64 + schunk * 8,
                         dst + p * 4096 + wave * 1024);
                gl2lds16(Vtb + ((size_t)bh * 64 + row) * T_ + s1 + schunk * 8,
                         dst + 8192 + p * 4096 + wave * 1024);
            }
        }
        const char* KsB = smem + ((st - st0) & 1) * 16384;
        const char* VtB = KsB + 8192;

        f32x4 accS[4];
#pragma unroll
        for (int n = 0; n < 4; ++n) accS[n] = (f32x4){0.f, 0.f, 0.f, 0.f};
        __builtin_amdgcn_s_setprio(1);
#pragma unroll
        for (int n = 0; n < 4; ++n) {
#pragma unroll
            for (int kk = 0; kk < 2; ++kk) {
                short8 bf = *(const short8*)(KsB + (n * 16 + l15) * 128 + ((kk * 64 + kchunk) ^ rsw));
                accS[n] = __builtin_amdgcn_mfma_f32_16x16x32_bf16(qf[kk], bf, accS[n], 0, 0, 0);
            }
        }
        __builtin_amdgcn_s_setprio(0);

        const bool last = (st == bt);
        char* PsW = PsB + wave * 2048;
#pragma unroll
        for (int n = 0; n < 4; ++n) {
#pragma unroll
            for (int r = 0; r < 4; ++r) {
                const float a = accS[n][r];
                float p = a * a;
                if (last)
                    p = ((n * 16 + l15) <= wave * 16 + lhi * 4 + r) ? p : 0.f;
                den[r] += p;
                const int prow = lhi * 4 + r;
                *(unsigned short*)(PsW + prow * 128 + ((2 * (n * 16 + l15)) ^ ((prow & 7) << 4))) = f2b(p);
            }
        }

        short8 pa[2];
#pragma unroll
        for (int kk = 0; kk < 2; ++kk)
            pa[kk] = *(const short8*)(PsW + l15 * 128 + ((kk * 64 + kchunk) ^ rsw));
        __builtin_amdgcn_s_setprio(1);
#pragma unroll
        for (int n = 0; n < 4; ++n) {
#pragma unroll
            for (int kk = 0; kk < 2; ++kk) {
                short8 vb = *(const short8*)(VtB + (n * 16 + l15) * 128 + ((kk * 64 + kchunk) ^ rsw));
                accY[n] = __builtin_amdgcn_mfma_f32_16x16x32_bf16(pa[kk], vb, accY[n], 0, 0, 0);
            }
        }
        __builtin_amdgcn_s_setprio(0);
    }

#pragma unroll
    for (int r = 0; r < 4; ++r) {
        den[r] += __shfl_xor(den[r], 1, 64);
        den[r] += __shfl_xor(den[r], 2, 64);
        den[r] += __shfl_xor(den[r], 4, 64);
        den[r] += __shfl_xor(den[r], 8, 64);
    }

    unsigned short* Ybase = Ypb + (size_t)sc * MC_;
    float* Dbase = Dpart + (size_t)sc * BHT_;
#pragma unroll
    for (int r = 0; r < 4; ++r) {
        const int t = t0 + wave * 16 + lhi * 4 + r;
        if (l15 == 0)
            Dbase[(size_t)bh * T_ + t] = den[r];
        unsigned short* yo = Ybase + (size_t)(b * T_ + t) * (H_ * D_) + h * 64 + l15;
#pragma unroll
        for (int n = 0; n < 4; ++n)
            yo[n * 16] = f2b(accY[n][r]);
    }
}

// ---------------------------------------------------------------------------
// normalize: ybb = bf16((sum of nsc bf16 Y slices) / max(sum den, 1e-6)),
// PRE-SWIZZLED. nsc = (t>>9)+1 for row-tile bt = t/64.
// ---------------------------------------------------------------------------
__global__ __launch_bounds__(256) void normalize_kernel(
    const unsigned short* __restrict__ Ypb, const float* __restrict__ Dpart,
    unsigned short* __restrict__ ybb)
{
    const int gid = blockIdx.x * 256 + threadIdx.x;
    const size_t base = (size_t)gid * 8;
    const int row = (int)(base >> 9);
    const int col = (int)(base & 511);
    const int b = row >> 11, t = row & 2047, h = col >> 6;
    const int bh = b * H_ + h;
    const int nsc = (t >> 9) + 1;

    float acc[8] = {0.f, 0.f, 0.f, 0.f, 0.f, 0.f, 0.f, 0.f};
    float d = 0.f;
    for (int s = 0; s < nsc; ++s) {
        d += Dpart[(size_t)s * BHT_ + (size_t)bh * T_ + t];
        short8 v = *(const short8*)(Ypb + (size_t)s * MC_ + base);
#pragma unroll
        for (int j = 0; j < 8; ++j)
            acc[j] += b2f((unsigned short)v[j]);
    }
    const float inv = 1.0f / fmaxf(d, 1e-6f);
    float4 f0 = make_float4(acc[0] * inv, acc[1] * inv, acc[2] * inv, acc[3] * inv);
    float4 f1 = make_float4(acc[4] * inv, acc[5] * inv, acc[6] * inv, acc[7] * inv);

    const int ic = col >> 3;
    const int swc = (ic & ~7) | ((ic & 7) ^ (row & 7));
    *(short8*)(ybb + (size_t)row * 512 + swc * 8) = pack8(f0, f1);
}

// ---------------------------------------------------------------------------
extern "C" void kernel_launch(void* const* d_in, const int* in_sizes, int n_in,
                              void* d_out, int out_size, void* d_ws, size_t ws_size,
                              hipStream_t stream)
{
    const float* x      = (const float*)d_in[0];
    const float* w_attn = (const float*)d_in[1];
    const float* w_proj = (const float*)d_in[2];
    float* out = (float*)d_out;

    // workspace (~39 MB of ~256 MB), no aliasing:
    char* p = (char*)d_ws;
    float2* sincos = (float2*)p;               p += (size_t)T_ * 32 * 8;       // 512 KB
    float* g       = (float*)p;                p += (size_t)BHT_ * 4;          // 128 KB
    float* Lg      = (float*)p;                p += (size_t)BHT_ * 4;          // 128 KB
    float* Dpart   = (float*)p;                p += (size_t)4 * BHT_ * 4;      // 512 KB
    unsigned short* xb  = (unsigned short*)p;  p += (size_t)MC_ * 2;           // 4 MB
    unsigned short* Bt1 = (unsigned short*)p;  p += (size_t)N1_ * C_ * 2;      // 1.5 MB
    unsigned short* Bt2 = (unsigned short*)p;  p += (size_t)C_ * C_ * 2;       // 0.5 MB
    unsigned short* Qsb = (unsigned short*)p;  p += (size_t)BHT_ * 64 * 2;     // 4 MB
    unsigned short* Ksb = (unsigned short*)p;  p += (size_t)BHT_ * 64 * 2;     // 4 MB
    unsigned short* Vtb = (unsigned short*)p;  p += (size_t)BHT_ * 64 * 2;     // 4 MB
    unsigned short* Ypb = (unsigned short*)p;  p += (size_t)4 * MC_ * 2;       // 16 MB
    unsigned short* ybb = (unsigned short*)p;                                  // 4 MB

    const int M = B_ * T_;      // 4096

    // 0) packs + sincos table + gate GEMV
    pack_inputs<<<1416, 256, 0, stream>>>(x, w_attn, w_proj, xb, Bt1, Bt2, sincos, g);

    // 1) gate log-sigmoid + cumsum -> Lg
    gate_cumsum<<<B_ * H_, 256, 0, stream>>>(g, Lg);

    // 2) fused qkv GEMM + RoPE/prescale/transpose epilogue -> Qsb, Ksb, Vtb
    gemm_fused<<<dim3(N1_ / 128, M / 128), 256, 0, stream>>>(
        xb, Bt1, Lg, sincos, Qsb, Ksb, Vtb);

    // 3) split-s attention (QBLK=64), bf16 partial slices
    attn_mfma<<<NBLK_, 256, 0, stream>>>(Qsb, Ksb, Vtb, Ypb, Dpart);

    // 4) normalize + slice-sum -> ybb (bf16, pre-swizzled)
    normalize_kernel<<<(MC_ / 8) / 256, 256, 0, stream>>>(Ypb, Dpart, ybb);

    // 5) out = ybb @ w_proj  (64x128 tiles, 256 blocks)
    gemm_bf16<<<dim3(C_ / 128, M / 64), 256, 0, stream>>>(
        ybb, Bt2, out, M, C_, H_ * D_);
}